// Round 6
// baseline (4984.103 us; speedup 1.0000x reference)
//
#include <hip/hip_runtime.h>
#include <stdint.h>

#define TT 8192
#define HD 2048
#define FFN 5632
#define NE 8
#define NPK 11264   // packed [w1;w2] rows per expert

typedef float f32x4 __attribute__((ext_vector_type(4)));
typedef _Float16 f16x8 __attribute__((ext_vector_type(8)));
typedef unsigned int u32;

// workspace layout (bytes)
#define OFF_WR    0ul
#define OFF_CNT   65536ul
#define OFF_LISTS 66048ul
#define OFF_TOKW  328192ul
#define OFF_ACT   1048576ul                    // 16384*5632*2      = 184549376
#define OFF_XH    (OFF_ACT + 184549376ul)      // 8192*2048*2       = 33554432
#define OFF_WPK   (OFF_XH + 33554432ul)        // 8*11264*2048*2    = 369098752
#define OFF_W3H   OFF_WPK                      // fc2h reuses WPK (stream-ordered)
// total = 588251136 (~561 MiB), same footprint as R4 (ran fine)

__device__ __forceinline__ void gl_lds16(const void* g, void* s) {
  __builtin_amdgcn_global_load_lds((const __attribute__((address_space(1))) u32*)g,
                                   (__attribute__((address_space(3))) u32*)s, 16, 0, 0);
}

#define VMCNT8() asm volatile("s_waitcnt vmcnt(8)" ::: "memory")
#define VMCNT4() asm volatile("s_waitcnt vmcnt(4)" ::: "memory")
#define VMCNT0() asm volatile("s_waitcnt vmcnt(0)" ::: "memory")
#define BARRIER() __builtin_amdgcn_s_barrier()
#define SCHEDB() __builtin_amdgcn_sched_barrier(0)

__device__ __forceinline__ f16x8 cvt8(f32x4 a, f32x4 b) {
  f16x8 r;
  r[0] = (_Float16)a[0]; r[1] = (_Float16)a[1]; r[2] = (_Float16)a[2]; r[3] = (_Float16)a[3];
  r[4] = (_Float16)b[0]; r[5] = (_Float16)b[1]; r[6] = (_Float16)b[2]; r[7] = (_Float16)b[3];
  return r;
}

__global__ __launch_bounds__(256) void k_cvt(const float* __restrict__ in,
                                             _Float16* __restrict__ out, long n8) {
  long i = (long)blockIdx.x * 256 + threadIdx.x;
  const long stride = (long)gridDim.x * 256;
  for (; i < n8; i += stride) {
    f32x4 a = ((const f32x4*)in)[i * 2];
    f32x4 b = ((const f32x4*)in)[i * 2 + 1];
    ((f16x8*)out)[i] = cvt8(a, b);
  }
}

// pack [fc1_1; fc1_2] into wpk[e][q][k]: q = ct*256 + wn*64 + half*32 + i,
// f = ct*128 + wn*32 + i  ->  silu-pairing lands in-register (ni <-> ni+2).
__global__ __launch_bounds__(256) void k_cvtpack(const float* __restrict__ fc11,
                                                 const float* __restrict__ fc12,
                                                 _Float16* __restrict__ wpk) {
  const long total = (long)NE * NPK * 256;  // 8-elem chunks
  long i8 = (long)blockIdx.x * 256 + threadIdx.x;
  const long stride = (long)gridDim.x * 256;
  for (; i8 < total; i8 += stride) {
    int k8 = (int)(i8 & 255);
    long qe = i8 >> 8;
    int q = (int)(qe % NPK);
    int e = (int)(qe / NPK);
    int f = (q >> 8) * 128 + ((q >> 6) & 3) * 32 + (q & 31);
    const float* src = (((q >> 5) & 1) ? fc12 : fc11) + ((size_t)e * FFN + f) * HD + k8 * 8;
    f32x4 a = *(const f32x4*)src;
    f32x4 b = *(const f32x4*)(src + 4);
    *(f16x8*)(wpk + qe * HD + (size_t)k8 * 8) = cvt8(a, b);
  }
}

__global__ __launch_bounds__(256) void k_prep(const float* __restrict__ wg,
                                              const float* __restrict__ wge,
                                              float* __restrict__ wr) {
  int i = blockIdx.x * 256 + threadIdx.x;
  if (i < HD * NE) wr[i] = 0.5f * (wge[i] + wg[i]);
}

__global__ __launch_bounds__(256) void k_router(const float* __restrict__ x,
                                                const float* __restrict__ wr,
                                                float* __restrict__ logits,
                                                float* __restrict__ tokw,
                                                int* __restrict__ lists,
                                                int* __restrict__ cnt) {
  const int t = blockIdx.x, tid = threadIdx.x;
  const float* xr = x + (size_t)t * HD;
  float acc[NE];
#pragma unroll
  for (int e = 0; e < NE; ++e) acc[e] = 0.f;
  for (int h = tid; h < HD; h += 256) {
    float xv = xr[h];
    const float* w = wr + h * NE;
#pragma unroll
    for (int e = 0; e < NE; ++e) acc[e] = fmaf(xv, w[e], acc[e]);
  }
#pragma unroll
  for (int e = 0; e < NE; ++e)
#pragma unroll
    for (int off = 32; off; off >>= 1)
      acc[e] += __shfl_xor(acc[e], off, 64);
  __shared__ float red[4][NE];
  int wv = tid >> 6;
  if ((tid & 63) == 0)
    for (int e = 0; e < NE; ++e) red[wv][e] = acc[e];
  __syncthreads();
  if (tid == 0) {
    float l[NE];
#pragma unroll
    for (int e = 0; e < NE; ++e) l[e] = red[0][e] + red[1][e] + red[2][e] + red[3][e];
#pragma unroll
    for (int e = 0; e < NE; ++e) logits[(size_t)t * NE + e] = l[e];
    int i0 = 0;
    for (int e = 1; e < NE; ++e) if (l[e] > l[i0]) i0 = e;
    int i1 = -1;
    for (int e = 0; e < NE; ++e) if (e != i0 && (i1 < 0 || l[e] > l[i1])) i1 = e;
    float p1 = __expf(l[i1] - l[i0]);
    float s = 1.f + p1;
    tokw[t * 2]     = 1.f / s;
    tokw[t * 2 + 1] = p1 / s;
    int q0 = atomicAdd(&cnt[i0], 1);
    lists[i0 * TT + q0] = t * 2;
    int q1 = atomicAdd(&cnt[i1], 1);
    lists[i1 * TT + q1] = t * 2 + 1;
  }
}

// ============ Stage A: act = silu(h1)*h2, h = xh @ wpk^T (gathered rows) ============
// 256x256 tile, 8 waves (2Mx4N), k-ring of 4 slots [256 rows][32 k] fp16.
// Per phase: 12 ds_read_b128 | stage k-half s+3 (4 gl_lds) | vmcnt(8) | bar | 32 MFMA | bar.
__global__ __launch_bounds__(512, 1) void k_ffn1(const _Float16* __restrict__ xh,
                                                 const _Float16* __restrict__ wpk,
                                                 const int* __restrict__ lists,
                                                 const int* __restrict__ cnt,
                                                 _Float16* __restrict__ act) {
  const int rt = blockIdx.x, ct = blockIdx.y, e = blockIdx.z;
  const int count = cnt[e];
  if (rt * 256 >= count) return;
  const int tid = threadIdx.x, lane = tid & 63, wv = tid >> 6;

  __shared__ __align__(16) _Float16 Asl[4][8192];
  __shared__ __align__(16) _Float16 Bsl[4][8192];
  __shared__ int row_pair[256];

  if (tid < 256) {
    int rg = rt * 256 + tid;
    row_pair[tid] = (rg < count) ? lists[e * TT + rg] : -1;
  }
  __syncthreads();

  // staging: thread handles rows (srow, srow+128) of A and B, fixed 16B k-chunk c16
  const int srow = tid >> 2;
  const int c16 = (tid & 3) ^ ((srow >> 1) & 3);
  const int prA0 = row_pair[srow], prA1 = row_pair[srow + 128];
  const _Float16* gA0 = xh + (size_t)(prA0 >= 0 ? (prA0 >> 1) : 0) * HD + c16 * 8;
  const _Float16* gA1 = xh + (size_t)(prA1 >= 0 ? (prA1 >> 1) : 0) * HD + c16 * 8;
  const _Float16* gB0 = wpk + ((size_t)e * NPK + (size_t)ct * 256 + srow) * HD + c16 * 8;
  const _Float16* gB1 = gB0 + (size_t)128 * HD;
  const int dof = wv * 512;

  const int wm = wv >> 2, wn = wv & 3;
  const int fr = lane & 15, kg = lane >> 4;
  int aoff[8], boff[4];
#pragma unroll
  for (int mi = 0; mi < 8; ++mi) {
    int r = wm * 128 + mi * 16 + fr;
    aoff[mi] = r * 32 + ((kg ^ ((r >> 1) & 3)) << 3);
  }
#pragma unroll
  for (int ni = 0; ni < 4; ++ni) {
    int r = wn * 64 + ni * 16 + fr;
    boff[ni] = r * 32 + ((kg ^ ((r >> 1) & 3)) << 3);
  }

  const f32x4 z4 = {0.f, 0.f, 0.f, 0.f};
  f32x4 acc[8][4];
#pragma unroll
  for (int mi = 0; mi < 8; ++mi)
#pragma unroll
    for (int ni = 0; ni < 4; ++ni) acc[mi][ni] = z4;

#define STAGE1(SL, KH)                                   \
  do {                                                   \
    gl_lds16(gA0 + (KH) * 32, &Asl[SL][dof]);            \
    gl_lds16(gA1 + (KH) * 32, &Asl[SL][dof + 4096]);     \
    gl_lds16(gB0 + (KH) * 32, &Bsl[SL][dof]);            \
    gl_lds16(gB1 + (KH) * 32, &Bsl[SL][dof + 4096]);     \
  } while (0)

  STAGE1(0, 0); STAGE1(1, 1); STAGE1(2, 2);
  VMCNT8();
  BARRIER(); SCHEDB();

  const int NS = HD / 32;  // 64
  for (int s = 0; s < NS; ++s) {
    const int slot = s & 3;
    f16x8 fa[8], fb[4];
#pragma unroll
    for (int mi = 0; mi < 8; ++mi) fa[mi] = *(const f16x8*)&Asl[slot][aoff[mi]];
#pragma unroll
    for (int ni = 0; ni < 4; ++ni) fb[ni] = *(const f16x8*)&Bsl[slot][boff[ni]];
    if (s + 3 < NS) { STAGE1((s + 3) & 3, s + 3); VMCNT8(); }
    else if (s == NS - 3) { VMCNT4(); }
    else if (s == NS - 2) { VMCNT0(); }
    BARRIER(); SCHEDB();
    __builtin_amdgcn_s_setprio(1);
#pragma unroll
    for (int mi = 0; mi < 8; ++mi)
#pragma unroll
      for (int ni = 0; ni < 4; ++ni)
        acc[mi][ni] = __builtin_amdgcn_mfma_f32_16x16x32_f16(fa[mi], fb[ni], acc[mi][ni], 0, 0, 0);
    __builtin_amdgcn_s_setprio(0);
    SCHEDB();
    BARRIER(); SCHEDB();
  }
#undef STAGE1

  // epilogue: cols 0-31 of wave window = h1, 32-63 = h2 (packed), pair ni <-> ni+2
  const int rof = kg * 4;
#pragma unroll
  for (int mi = 0; mi < 8; ++mi) {
#pragma unroll
    for (int ni = 0; ni < 2; ++ni) {
      const int f = ct * 128 + wn * 32 + ni * 16 + fr;
#pragma unroll
      for (int j = 0; j < 4; ++j) {
        int row = wm * 128 + mi * 16 + rof + j;
        int pr = row_pair[row];
        if (pr >= 0) {
          float h1 = acc[mi][ni][j], h2 = acc[mi][ni + 2][j];
          float sv = h1 / (1.f + __expf(-h1));
          act[(size_t)pr * FFN + f] = (_Float16)(sv * h2);
        }
      }
    }
  }
}

// ============ Stage B: out += w * (act @ w3h^T) ============
__global__ __launch_bounds__(512, 1) void k_ffn2(const _Float16* __restrict__ act,
                                                 const _Float16* __restrict__ w3h,
                                                 const int* __restrict__ lists,
                                                 const int* __restrict__ cnt,
                                                 const float* __restrict__ tokw,
                                                 float* __restrict__ out) {
  const int rt = blockIdx.x, ct = blockIdx.y, e = blockIdx.z;
  const int count = cnt[e];
  if (rt * 256 >= count) return;
  const int tid = threadIdx.x, lane = tid & 63, wv = tid >> 6;

  __shared__ __align__(16) _Float16 Asl[4][8192];
  __shared__ __align__(16) _Float16 Bsl[4][8192];
  __shared__ int row_pair[256];
  __shared__ float row_w[256];

  if (tid < 256) {
    int rg = rt * 256 + tid;
    int pr = (rg < count) ? lists[e * TT + rg] : -1;
    row_pair[tid] = pr;
    row_w[tid] = (pr >= 0) ? tokw[pr] : 0.f;
  }
  __syncthreads();

  const int srow = tid >> 2;
  const int c16 = (tid & 3) ^ ((srow >> 1) & 3);
  const int prA0 = row_pair[srow], prA1 = row_pair[srow + 128];
  const _Float16* gA0 = act + (size_t)(prA0 >= 0 ? prA0 : 0) * FFN + c16 * 8;
  const _Float16* gA1 = act + (size_t)(prA1 >= 0 ? prA1 : 0) * FFN + c16 * 8;
  const _Float16* gB0 = w3h + ((size_t)e * HD + (size_t)ct * 256 + srow) * FFN + c16 * 8;
  const _Float16* gB1 = gB0 + (size_t)128 * FFN;
  const int dof = wv * 512;

  const int wm = wv >> 2, wn = wv & 3;
  const int fr = lane & 15, kg = lane >> 4;
  int aoff[8], boff[4];
#pragma unroll
  for (int mi = 0; mi < 8; ++mi) {
    int r = wm * 128 + mi * 16 + fr;
    aoff[mi] = r * 32 + ((kg ^ ((r >> 1) & 3)) << 3);
  }
#pragma unroll
  for (int ni = 0; ni < 4; ++ni) {
    int r = wn * 64 + ni * 16 + fr;
    boff[ni] = r * 32 + ((kg ^ ((r >> 1) & 3)) << 3);
  }

  const f32x4 z4 = {0.f, 0.f, 0.f, 0.f};
  f32x4 acc[8][4];
#pragma unroll
  for (int mi = 0; mi < 8; ++mi)
#pragma unroll
    for (int ni = 0; ni < 4; ++ni) acc[mi][ni] = z4;

#define STAGE2(SL, KH)                                   \
  do {                                                   \
    gl_lds16(gA0 + (KH) * 32, &Asl[SL][dof]);            \
    gl_lds16(gA1 + (KH) * 32, &Asl[SL][dof + 4096]);     \
    gl_lds16(gB0 + (KH) * 32, &Bsl[SL][dof]);            \
    gl_lds16(gB1 + (KH) * 32, &Bsl[SL][dof + 4096]);     \
  } while (0)

  STAGE2(0, 0); STAGE2(1, 1); STAGE2(2, 2);
  VMCNT8();
  BARRIER(); SCHEDB();

  const int NS = FFN / 32;  // 176
  for (int s = 0; s < NS; ++s) {
    const int slot = s & 3;
    f16x8 fa[8], fb[4];
#pragma unroll
    for (int mi = 0; mi < 8; ++mi) fa[mi] = *(const f16x8*)&Asl[slot][aoff[mi]];
#pragma unroll
    for (int ni = 0; ni < 4; ++ni) fb[ni] = *(const f16x8*)&Bsl[slot][boff[ni]];
    if (s + 3 < NS) { STAGE2((s + 3) & 3, s + 3); VMCNT8(); }
    else if (s == NS - 3) { VMCNT4(); }
    else if (s == NS - 2) { VMCNT0(); }
    BARRIER(); SCHEDB();
    __builtin_amdgcn_s_setprio(1);
#pragma unroll
    for (int mi = 0; mi < 8; ++mi)
#pragma unroll
      for (int ni = 0; ni < 4; ++ni)
        acc[mi][ni] = __builtin_amdgcn_mfma_f32_16x16x32_f16(fa[mi], fb[ni], acc[mi][ni], 0, 0, 0);
    __builtin_amdgcn_s_setprio(0);
    SCHEDB();
    BARRIER(); SCHEDB();
  }
#undef STAGE2

  const int rof = kg * 4;
#pragma unroll
  for (int mi = 0; mi < 8; ++mi) {
#pragma unroll
    for (int ni = 0; ni < 4; ++ni) {
      const int col = ct * 256 + wn * 64 + ni * 16 + fr;
#pragma unroll
      for (int j = 0; j < 4; ++j) {
        int row = wm * 128 + mi * 16 + rof + j;
        int pr = row_pair[row];
        if (pr >= 0) {
          float v = acc[mi][ni][j] * row_w[row];
          unsafeAtomicAdd(out + (size_t)(pr >> 1) * HD + col, v);
        }
      }
    }
  }
}

extern "C" void kernel_launch(void* const* d_in, const int* in_sizes, int n_in,
                              void* d_out, int out_size, void* d_ws, size_t ws_size,
                              hipStream_t stream) {
  (void)in_sizes; (void)n_in; (void)out_size; (void)ws_size;
  const float* x    = (const float*)d_in[0];
  const float* wg   = (const float*)d_in[1];
  const float* wge  = (const float*)d_in[2];
  const float* fc11 = (const float*)d_in[3];
  const float* fc12 = (const float*)d_in[4];
  const float* fc2  = (const float*)d_in[5];
  float* out    = (float*)d_out;
  float* logits = out + (size_t)TT * HD;

  char* ws = (char*)d_ws;
  float* wr      = (float*)(ws + OFF_WR);
  int*   cnt     = (int*)(ws + OFF_CNT);
  int*   lists   = (int*)(ws + OFF_LISTS);
  float* tokw    = (float*)(ws + OFF_TOKW);
  _Float16* act  = (_Float16*)(ws + OFF_ACT);
  _Float16* xh   = (_Float16*)(ws + OFF_XH);
  _Float16* wpk  = (_Float16*)(ws + OFF_WPK);
  _Float16* w3h  = (_Float16*)(ws + OFF_W3H);

  hipMemsetAsync(out, 0, (size_t)TT * HD * sizeof(float), stream);
  hipMemsetAsync(cnt, 0, NE * sizeof(int), stream);

  k_prep<<<dim3((HD * NE + 255) / 256), 256, 0, stream>>>(wg, wge, wr);
  k_router<<<dim3(TT), 256, 0, stream>>>(x, wr, logits, tokw, lists, cnt);

  k_cvt<<<dim3(2048), 256, 0, stream>>>(x, xh, (long)TT * HD / 8);
  k_cvtpack<<<dim3(2048), 256, 0, stream>>>(fc11, fc12, wpk);

  k_ffn1<<<dim3(TT / 256, NPK / 256, NE), 512, 0, stream>>>(xh, wpk, lists, cnt, act);

  // w3h reuses the wpk region — stream-ordered after ffn1 finished reading it
  k_cvt<<<dim3(2048), 256, 0, stream>>>(fc2, w3h, (long)NE * HD * FFN / 8);

  k_ffn2<<<dim3(TT / 256, HD / 256, NE), 512, 0, stream>>>(act, w3h, lists, cnt, tokw, out);
}

// Round 7
// 3083.155 us; speedup vs baseline: 1.6166x; 1.6166x over previous
//
#include <hip/hip_runtime.h>
#include <stdint.h>

#define TT 8192
#define HD 2048
#define FFN 5632
#define NE 8
#define NPK 11264   // packed [w1|w2] rows per expert (2*FFN)

typedef float f32x4 __attribute__((ext_vector_type(4)));
typedef _Float16 f16x8 __attribute__((ext_vector_type(8)));
typedef unsigned int u32;

// workspace layout (bytes)
#define OFF_WR    0ul
#define OFF_CNT   65536ul
#define OFF_LISTS 66048ul
#define OFF_TOKW  328192ul
#define OFF_ACT   1048576ul                    // 16384*5632*2      = 184549376
#define OFF_XH    (OFF_ACT + 184549376ul)      // 8192*2048*2       = 33554432
#define OFF_WPK   (OFF_XH + 33554432ul)        // 8*11264*2048*2    = 369098752
#define OFF_W3H   OFF_WPK                      // fc2h reuses WPK (stream-ordered)

__device__ __forceinline__ void gl_lds16(const void* g, void* s) {
  __builtin_amdgcn_global_load_lds((const __attribute__((address_space(1))) u32*)g,
                                   (__attribute__((address_space(3))) u32*)s, 16, 0, 0);
}

#define VMCNT4() asm volatile("s_waitcnt vmcnt(4)" ::: "memory")
#define VMCNT0() asm volatile("s_waitcnt vmcnt(0)" ::: "memory")
#define BARRIER() __builtin_amdgcn_s_barrier()

__device__ __forceinline__ f16x8 cvt8(f32x4 a, f32x4 b) {
  f16x8 r;
  r[0] = (_Float16)a[0]; r[1] = (_Float16)a[1]; r[2] = (_Float16)a[2]; r[3] = (_Float16)a[3];
  r[4] = (_Float16)b[0]; r[5] = (_Float16)b[1]; r[6] = (_Float16)b[2]; r[7] = (_Float16)b[3];
  return r;
}

__global__ __launch_bounds__(256) void k_cvt(const float* __restrict__ in,
                                             _Float16* __restrict__ out, long n8) {
  long i = (long)blockIdx.x * 256 + threadIdx.x;
  const long stride = (long)gridDim.x * 256;
  for (; i < n8; i += stride) {
    f32x4 a = ((const f32x4*)in)[i * 2];
    f32x4 b = ((const f32x4*)in)[i * 2 + 1];
    ((f16x8*)out)[i] = cvt8(a, b);
  }
}

// pack [fc1_1 | fc1_2] -> wpk. For 128-col tile ct, local col c:
// wn=(c>>6)&1, n=(c>>4)&3, fr=c&15 ; f = ct*64 + wn*32 + (n&1)*16 + fr ; n>=2 -> fc1_2.
__global__ __launch_bounds__(256) void k_cvtpack(const float* __restrict__ fc11,
                                                 const float* __restrict__ fc12,
                                                 _Float16* __restrict__ wpk) {
  const long total = (long)NE * NPK * 256;  // 8-elem chunks
  long i8 = (long)blockIdx.x * 256 + threadIdx.x;
  const long stride = (long)gridDim.x * 256;
  for (; i8 < total; i8 += stride) {
    int k8 = (int)(i8 & 255);
    long qe = i8 >> 8;
    int q = (int)(qe % NPK);
    int e = (int)(qe / NPK);
    int c = q & 127;
    int f = (q >> 7) * 64 + ((c >> 6) & 1) * 32 + ((c >> 4) & 1) * 16 + (c & 15);
    const float* src = ((c >> 5) & 1 ? fc12 : fc11) + ((size_t)e * FFN + f) * HD + k8 * 8;
    f32x4 a = *(const f32x4*)src;
    f32x4 b = *(const f32x4*)(src + 4);
    *(f16x8*)(wpk + qe * HD + (size_t)k8 * 8) = cvt8(a, b);
  }
}

__global__ __launch_bounds__(256) void k_prep(const float* __restrict__ wg,
                                              const float* __restrict__ wge,
                                              float* __restrict__ wr) {
  int i = blockIdx.x * 256 + threadIdx.x;
  if (i < HD * NE) wr[i] = 0.5f * (wge[i] + wg[i]);
}

__global__ __launch_bounds__(256) void k_router(const float* __restrict__ x,
                                                const float* __restrict__ wr,
                                                float* __restrict__ logits,
                                                float* __restrict__ tokw,
                                                int* __restrict__ lists,
                                                int* __restrict__ cnt) {
  const int t = blockIdx.x, tid = threadIdx.x;
  const float* xr = x + (size_t)t * HD;
  float acc[NE];
#pragma unroll
  for (int e = 0; e < NE; ++e) acc[e] = 0.f;
  for (int h = tid; h < HD; h += 256) {
    float xv = xr[h];
    const float* w = wr + h * NE;
#pragma unroll
    for (int e = 0; e < NE; ++e) acc[e] = fmaf(xv, w[e], acc[e]);
  }
#pragma unroll
  for (int e = 0; e < NE; ++e)
#pragma unroll
    for (int off = 32; off; off >>= 1)
      acc[e] += __shfl_xor(acc[e], off, 64);
  __shared__ float red[4][NE];
  int wv = tid >> 6;
  if ((tid & 63) == 0)
    for (int e = 0; e < NE; ++e) red[wv][e] = acc[e];
  __syncthreads();
  if (tid == 0) {
    float l[NE];
#pragma unroll
    for (int e = 0; e < NE; ++e) l[e] = red[0][e] + red[1][e] + red[2][e] + red[3][e];
#pragma unroll
    for (int e = 0; e < NE; ++e) logits[(size_t)t * NE + e] = l[e];
    int i0 = 0;
    for (int e = 1; e < NE; ++e) if (l[e] > l[i0]) i0 = e;
    int i1 = -1;
    for (int e = 0; e < NE; ++e) if (e != i0 && (i1 < 0 || l[e] > l[i1])) i1 = e;
    float p1 = __expf(l[i1] - l[i0]);
    float s = 1.f + p1;
    tokw[t * 2]     = 1.f / s;
    tokw[t * 2 + 1] = p1 / s;
    int q0 = atomicAdd(&cnt[i0], 1);
    lists[i0 * TT + q0] = t * 2;
    int q1 = atomicAdd(&cnt[i1], 1);
    lists[i1 * TT + q1] = t * 2 + 1;
  }
}

// ============ Stage A: act = silu(h1)*h2, h = xh @ wpk^T (gathered rows) ============
// 128x128 tile, BK=32, 4 waves 2x2 (wave 64x64), 3-slot ring, prefetch-2, vmcnt(4).
// LDS chunk perm within 64B row: c' = c ^ ((row>>1)&3) -> 2-way banks, coalescing kept.
__global__ __launch_bounds__(256, 3) void k_ffn1(const _Float16* __restrict__ xh,
                                                 const _Float16* __restrict__ wpk,
                                                 const int* __restrict__ lists,
                                                 const int* __restrict__ cnt,
                                                 _Float16* __restrict__ act) {
  const int rt = blockIdx.x, ct = blockIdx.y, e = blockIdx.z;
  const int count = cnt[e];
  if (rt * 128 >= count) return;
  const int tid = threadIdx.x, lane = tid & 63, wv = tid >> 6;

  __shared__ __align__(16) _Float16 As[3][4096];
  __shared__ __align__(16) _Float16 Bs[3][4096];
  __shared__ int row_pair[128];

  if (tid < 128) {
    int rg = rt * 128 + tid;
    row_pair[tid] = (rg < count) ? lists[e * TT + rg] : -1;
  }
  __syncthreads();

  // staging: wave wv owns rows wv*32..wv*32+31 of A and of B (two 16-row instrs each)
  const int lr = lane >> 2;                     // 0..15
  const int srow = wv * 32 + lr;
  const int cp = (lane & 3) ^ ((srow >> 1) & 3); // chunk perm (same for srow and srow+16)
  const int p0 = row_pair[srow], p1 = row_pair[srow + 16];
  const _Float16* gA0 = xh + (size_t)(p0 >= 0 ? (p0 >> 1) : 0) * HD + cp * 8;
  const _Float16* gA1 = xh + (size_t)(p1 >= 0 ? (p1 >> 1) : 0) * HD + cp * 8;
  const _Float16* gB0 = wpk + ((size_t)e * NPK + (size_t)ct * 128 + srow) * HD + cp * 8;
  const _Float16* gB1 = gB0 + (size_t)16 * HD;

  auto stage = [&](int sl, int k0) {
    gl_lds16(gA0 + k0, &As[sl][wv * 1024]);
    gl_lds16(gA1 + k0, &As[sl][wv * 1024 + 512]);
    gl_lds16(gB0 + k0, &Bs[sl][wv * 1024]);
    gl_lds16(gB1 + k0, &Bs[sl][wv * 1024 + 512]);
  };

  const f32x4 z4 = {0.f, 0.f, 0.f, 0.f};
  f32x4 acc[4][4];
#pragma unroll
  for (int m = 0; m < 4; ++m)
#pragma unroll
    for (int n = 0; n < 4; ++n) acc[m][n] = z4;

  const int fr = lane & 15, kq = lane >> 4;
  const int wrow = (wv >> 1) * 64, wcol = (wv & 1) * 64;
  int aoff[4], boff[4];
#pragma unroll
  for (int m = 0; m < 4; ++m) {
    int r = wrow + m * 16 + fr;
    aoff[m] = r * 32 + (kq ^ ((r >> 1) & 3)) * 8;
  }
#pragma unroll
  for (int n = 0; n < 4; ++n) {
    int r = wcol + n * 16 + fr;
    boff[n] = r * 32 + (kq ^ ((r >> 1) & 3)) * 8;
  }

  stage(0, 0);
  stage(1, 32);
  VMCNT4();
  BARRIER();

  const int NS = HD / 32;  // 64
  int sl = 0, ss = 2;
  for (int s = 0; s < NS; ++s) {
    const bool pre = (s + 2 < NS);
    if (pre) stage(ss, (s + 2) * 32);
    f16x8 fa[4], fb[4];
#pragma unroll
    for (int m = 0; m < 4; ++m) fa[m] = *(const f16x8*)&As[sl][aoff[m]];
#pragma unroll
    for (int n = 0; n < 4; ++n) fb[n] = *(const f16x8*)&Bs[sl][boff[n]];
    __builtin_amdgcn_s_setprio(1);
#pragma unroll
    for (int m = 0; m < 4; ++m)
#pragma unroll
      for (int n = 0; n < 4; ++n)
        acc[m][n] = __builtin_amdgcn_mfma_f32_16x16x32_f16(fa[m], fb[n], acc[m][n], 0, 0, 0);
    __builtin_amdgcn_s_setprio(0);
    if (pre) { VMCNT4(); } else { VMCNT0(); }
    BARRIER();
    sl = (sl == 2) ? 0 : sl + 1;
    ss = (ss == 2) ? 0 : ss + 1;
  }

  // epilogue: packed cols -> h1 = acc[m][n], h2 = acc[m][n+2]; f = ct*64 + wn*32 + n*16 + fr
  const int wn = wv & 1;
  const int rbase = wrow + kq * 4;
#pragma unroll
  for (int m = 0; m < 4; ++m) {
#pragma unroll
    for (int n = 0; n < 2; ++n) {
      const int f = ct * 64 + wn * 32 + n * 16 + fr;
#pragma unroll
      for (int j = 0; j < 4; ++j) {
        int rl = rbase + m * 16 + j;
        int pr = row_pair[rl];
        if (pr >= 0) {
          float h1 = acc[m][n][j], h2 = acc[m][n + 2][j];
          float sv = h1 / (1.f + __expf(-h1));
          act[(size_t)pr * FFN + f] = (_Float16)(sv * h2);
        }
      }
    }
  }
}

// ============ Stage B: out += w * (act @ w3h^T). same structure ============
__global__ __launch_bounds__(256, 3) void k_ffn2(const _Float16* __restrict__ act,
                                                 const _Float16* __restrict__ w3h,
                                                 const int* __restrict__ lists,
                                                 const int* __restrict__ cnt,
                                                 const float* __restrict__ tokw,
                                                 float* __restrict__ out) {
  const int rt = blockIdx.x, ct = blockIdx.y, e = blockIdx.z;
  const int count = cnt[e];
  if (rt * 128 >= count) return;
  const int tid = threadIdx.x, lane = tid & 63, wv = tid >> 6;

  __shared__ __align__(16) _Float16 As[3][4096];
  __shared__ __align__(16) _Float16 Bs[3][4096];
  __shared__ int row_pair[128];
  __shared__ float row_w[128];

  if (tid < 128) {
    int rg = rt * 128 + tid;
    int pr = (rg < count) ? lists[e * TT + rg] : -1;
    row_pair[tid] = pr;
    row_w[tid] = (pr >= 0) ? tokw[pr] : 0.f;
  }
  __syncthreads();

  const int lr = lane >> 2;
  const int srow = wv * 32 + lr;
  const int cp = (lane & 3) ^ ((srow >> 1) & 3);
  const int p0 = row_pair[srow], p1 = row_pair[srow + 16];
  const _Float16* gA0 = act + (size_t)(p0 >= 0 ? p0 : 0) * FFN + cp * 8;
  const _Float16* gA1 = act + (size_t)(p1 >= 0 ? p1 : 0) * FFN + cp * 8;
  const _Float16* gB0 = w3h + ((size_t)e * HD + (size_t)ct * 128 + srow) * FFN + cp * 8;
  const _Float16* gB1 = gB0 + (size_t)16 * FFN;

  auto stage = [&](int sl, int k0) {
    gl_lds16(gA0 + k0, &As[sl][wv * 1024]);
    gl_lds16(gA1 + k0, &As[sl][wv * 1024 + 512]);
    gl_lds16(gB0 + k0, &Bs[sl][wv * 1024]);
    gl_lds16(gB1 + k0, &Bs[sl][wv * 1024 + 512]);
  };

  const f32x4 z4 = {0.f, 0.f, 0.f, 0.f};
  f32x4 acc[4][4];
#pragma unroll
  for (int m = 0; m < 4; ++m)
#pragma unroll
    for (int n = 0; n < 4; ++n) acc[m][n] = z4;

  const int fr = lane & 15, kq = lane >> 4;
  const int wrow = (wv >> 1) * 64, wcol = (wv & 1) * 64;
  int aoff[4], boff[4];
#pragma unroll
  for (int m = 0; m < 4; ++m) {
    int r = wrow + m * 16 + fr;
    aoff[m] = r * 32 + (kq ^ ((r >> 1) & 3)) * 8;
  }
#pragma unroll
  for (int n = 0; n < 4; ++n) {
    int r = wcol + n * 16 + fr;
    boff[n] = r * 32 + (kq ^ ((r >> 1) & 3)) * 8;
  }

  stage(0, 0);
  stage(1, 32);
  VMCNT4();
  BARRIER();

  const int NS = FFN / 32;  // 176
  int sl = 0, ss = 2;
  for (int s = 0; s < NS; ++s) {
    const bool pre = (s + 2 < NS);
    if (pre) stage(ss, (s + 2) * 32);
    f16x8 fa[4], fb[4];
#pragma unroll
    for (int m = 0; m < 4; ++m) fa[m] = *(const f16x8*)&As[sl][aoff[m]];
#pragma unroll
    for (int n = 0; n < 4; ++n) fb[n] = *(const f16x8*)&Bs[sl][boff[n]];
    __builtin_amdgcn_s_setprio(1);
#pragma unroll
    for (int m = 0; m < 4; ++m)
#pragma unroll
      for (int n = 0; n < 4; ++n)
        acc[m][n] = __builtin_amdgcn_mfma_f32_16x16x32_f16(fa[m], fb[n], acc[m][n], 0, 0, 0);
    __builtin_amdgcn_s_setprio(0);
    if (pre) { VMCNT4(); } else { VMCNT0(); }
    BARRIER();
    sl = (sl == 2) ? 0 : sl + 1;
    ss = (ss == 2) ? 0 : ss + 1;
  }

  const int rbase = wrow + kq * 4;
#pragma unroll
  for (int m = 0; m < 4; ++m) {
#pragma unroll
    for (int n = 0; n < 4; ++n) {
      const int col = ct * 128 + wcol + n * 16 + fr;
#pragma unroll
      for (int j = 0; j < 4; ++j) {
        int rl = rbase + m * 16 + j;
        int pr = row_pair[rl];
        if (pr >= 0) {
          float v = acc[m][n][j] * row_w[rl];
          unsafeAtomicAdd(out + (size_t)(pr >> 1) * HD + col, v);
        }
      }
    }
  }
}

extern "C" void kernel_launch(void* const* d_in, const int* in_sizes, int n_in,
                              void* d_out, int out_size, void* d_ws, size_t ws_size,
                              hipStream_t stream) {
  (void)in_sizes; (void)n_in; (void)out_size; (void)ws_size;
  const float* x    = (const float*)d_in[0];
  const float* wg   = (const float*)d_in[1];
  const float* wge  = (const float*)d_in[2];
  const float* fc11 = (const float*)d_in[3];
  const float* fc12 = (const float*)d_in[4];
  const float* fc2  = (const float*)d_in[5];
  float* out    = (float*)d_out;
  float* logits = out + (size_t)TT * HD;

  char* ws = (char*)d_ws;
  float* wr      = (float*)(ws + OFF_WR);
  int*   cnt     = (int*)(ws + OFF_CNT);
  int*   lists   = (int*)(ws + OFF_LISTS);
  float* tokw    = (float*)(ws + OFF_TOKW);
  _Float16* act  = (_Float16*)(ws + OFF_ACT);
  _Float16* xh   = (_Float16*)(ws + OFF_XH);
  _Float16* wpk  = (_Float16*)(ws + OFF_WPK);
  _Float16* w3h  = (_Float16*)(ws + OFF_W3H);

  hipMemsetAsync(out, 0, (size_t)TT * HD * sizeof(float), stream);
  hipMemsetAsync(cnt, 0, NE * sizeof(int), stream);

  k_prep<<<dim3((HD * NE + 255) / 256), 256, 0, stream>>>(wg, wge, wr);
  k_router<<<dim3(TT), 256, 0, stream>>>(x, wr, logits, tokw, lists, cnt);

  k_cvt<<<dim3(2048), 256, 0, stream>>>(x, xh, (long)TT * HD / 8);
  k_cvtpack<<<dim3(2048), 256, 0, stream>>>(fc11, fc12, wpk);

  k_ffn1<<<dim3(TT / 128, NPK / 128, NE), 256, 0, stream>>>(xh, wpk, lists, cnt, act);

  // w3h reuses the wpk region — stream-ordered after ffn1 finished reading it
  k_cvt<<<dim3(2048), 256, 0, stream>>>(fc2, w3h, (long)NE * HD * FFN / 8);

  k_ffn2<<<dim3(TT / 128, HD / 128, NE), 256, 0, stream>>>(act, w3h, lists, cnt, tokw, out);
}

// Round 9
// 2293.099 us; speedup vs baseline: 2.1735x; 1.3445x over previous
//
#include <hip/hip_runtime.h>
#include <stdint.h>

#define TT 8192
#define HD 2048
#define FFN 5632
#define NE 8
#define NPK 11264   // packed [w1|w2] rows per expert (2*FFN)

typedef float f32x4 __attribute__((ext_vector_type(4)));
typedef _Float16 f16x8 __attribute__((ext_vector_type(8)));
typedef unsigned int u32;

// workspace layout (bytes)
#define OFF_WR    0ul
#define OFF_CNT   65536ul
#define OFF_LISTS 66048ul
#define OFF_TOKW  328192ul
#define OFF_ACT   1048576ul                    // 16384*5632*2      = 184549376
#define OFF_XH    (OFF_ACT + 184549376ul)      // 8192*2048*2       = 33554432
#define OFF_WPK   (OFF_XH + 33554432ul)        // 8*11264*2048*2    = 369098752
#define OFF_W3H   OFF_WPK                      // fc2h reuses WPK (stream-ordered)

__device__ __forceinline__ void gl_lds16(const void* g, void* s) {
  __builtin_amdgcn_global_load_lds((const __attribute__((address_space(1))) u32*)g,
                                   (__attribute__((address_space(3))) u32*)s, 16, 0, 0);
}

__device__ __forceinline__ f16x8 cvt8(f32x4 a, f32x4 b) {
  f16x8 r;
  r[0] = (_Float16)a[0]; r[1] = (_Float16)a[1]; r[2] = (_Float16)a[2]; r[3] = (_Float16)a[3];
  r[4] = (_Float16)b[0]; r[5] = (_Float16)b[1]; r[6] = (_Float16)b[2]; r[7] = (_Float16)b[3];
  return r;
}

__global__ __launch_bounds__(256) void k_cvt(const float* __restrict__ in,
                                             _Float16* __restrict__ out, long n8) {
  long i = (long)blockIdx.x * 256 + threadIdx.x;
  const long stride = (long)gridDim.x * 256;
  for (; i < n8; i += stride) {
    f32x4 a = ((const f32x4*)in)[i * 2];
    f32x4 b = ((const f32x4*)in)[i * 2 + 1];
    ((f16x8*)out)[i] = cvt8(a, b);
  }
}

// pack [fc1_1 | fc1_2] -> wpk (per 128-row tile: bit6 = wn, bit5 = which matrix, bit4 = n&1)
__global__ __launch_bounds__(256) void k_cvtpack(const float* __restrict__ fc11,
                                                 const float* __restrict__ fc12,
                                                 _Float16* __restrict__ wpk) {
  const long total = (long)NE * NPK * 256;  // 8-elem chunks
  long i8 = (long)blockIdx.x * 256 + threadIdx.x;
  const long stride = (long)gridDim.x * 256;
  for (; i8 < total; i8 += stride) {
    int k8 = (int)(i8 & 255);
    long qe = i8 >> 8;
    int q = (int)(qe % NPK);
    int e = (int)(qe / NPK);
    int c = q & 127;
    int f = (q >> 7) * 64 + ((c >> 6) & 1) * 32 + ((c >> 4) & 1) * 16 + (c & 15);
    const float* src = ((c >> 5) & 1 ? fc12 : fc11) + ((size_t)e * FFN + f) * HD + k8 * 8;
    f32x4 a = *(const f32x4*)src;
    f32x4 b = *(const f32x4*)(src + 4);
    *(f16x8*)(wpk + qe * HD + (size_t)k8 * 8) = cvt8(a, b);
  }
}

__global__ __launch_bounds__(256) void k_prep(const float* __restrict__ wg,
                                              const float* __restrict__ wge,
                                              float* __restrict__ wr) {
  int i = blockIdx.x * 256 + threadIdx.x;
  if (i < HD * NE) wr[i] = 0.5f * (wge[i] + wg[i]);
}

__global__ __launch_bounds__(256) void k_router(const float* __restrict__ x,
                                                const float* __restrict__ wr,
                                                float* __restrict__ logits,
                                                float* __restrict__ tokw,
                                                int* __restrict__ lists,
                                                int* __restrict__ cnt) {
  const int t = blockIdx.x, tid = threadIdx.x;
  const float* xr = x + (size_t)t * HD;
  float acc[NE];
#pragma unroll
  for (int e = 0; e < NE; ++e) acc[e] = 0.f;
  for (int h = tid; h < HD; h += 256) {
    float xv = xr[h];
    const float* w = wr + h * NE;
#pragma unroll
    for (int e = 0; e < NE; ++e) acc[e] = fmaf(xv, w[e], acc[e]);
  }
#pragma unroll
  for (int e = 0; e < NE; ++e)
#pragma unroll
    for (int off = 32; off; off >>= 1)
      acc[e] += __shfl_xor(acc[e], off, 64);
  __shared__ float red[4][NE];
  int wv = tid >> 6;
  if ((tid & 63) == 0)
    for (int e = 0; e < NE; ++e) red[wv][e] = acc[e];
  __syncthreads();
  if (tid == 0) {
    float l[NE];
#pragma unroll
    for (int e = 0; e < NE; ++e) l[e] = red[0][e] + red[1][e] + red[2][e] + red[3][e];
#pragma unroll
    for (int e = 0; e < NE; ++e) logits[(size_t)t * NE + e] = l[e];
    int i0 = 0;
    for (int e = 1; e < NE; ++e) if (l[e] > l[i0]) i0 = e;
    int i1 = -1;
    for (int e = 0; e < NE; ++e) if (e != i0 && (i1 < 0 || l[e] > l[i1])) i1 = e;
    float p1 = __expf(l[i1] - l[i0]);
    float s = 1.f + p1;
    tokw[t * 2]     = 1.f / s;
    tokw[t * 2 + 1] = p1 / s;
    int q0 = atomicAdd(&cnt[i0], 1);
    lists[i0 * TT + q0] = t * 2;
    int q1 = atomicAdd(&cnt[i1], 1);
    lists[i1 * TT + q1] = t * 2 + 1;
  }
}

// ============ Stage A: act = silu(h1)*h2, h = xh @ wpk^T (gathered rows) ============
// 128x128 tile, BK=32, 4 waves 2x2 (wave 64x64). Double-buffer + __syncthreads (R4-proven).
// LDS chunk perm within 64B row (R7-proven, 0 conflicts). Grid: linear, XCD-pinned panels.
__global__ __launch_bounds__(256, 3) void k_ffn1(const _Float16* __restrict__ xh,
                                                 const _Float16* __restrict__ wpk,
                                                 const int* __restrict__ lists,
                                                 const int* __restrict__ cnt,
                                                 _Float16* __restrict__ act) {
  // decode: xcd = bid&7 pinned to panel (ct,e) with (ct+e)%8 == xcd; rt consecutive
  const int bid = blockIdx.x;
  const int xk = bid & 7;
  const int sq = bid >> 3;
  const int rt = sq & 63;
  const int q  = sq >> 6;                       // 0..87
  const int e  = q & 7;
  const int ct = ((xk - e) & 7) + 8 * (q >> 3); // 0..87
  const int count = cnt[e];
  if (rt * 128 >= count) return;
  const int tid = threadIdx.x, lane = tid & 63, wv = tid >> 6;

  __shared__ __align__(16) _Float16 As[2][4096];
  __shared__ __align__(16) _Float16 Bs[2][4096];
  __shared__ int row_pair[128];

  if (tid < 128) {
    int rg = rt * 128 + tid;
    row_pair[tid] = (rg < count) ? lists[e * TT + rg] : -1;
  }
  __syncthreads();

  // staging: wave wv stages rows wv*32..+31 of A and B (2 gl_lds each), XOR chunk perm
  const int lr = lane >> 2;
  const int srow = wv * 32 + lr;
  const int cp = (lane & 3) ^ ((srow >> 1) & 3);
  const int p0 = row_pair[srow], p1 = row_pair[srow + 16];
  const _Float16* gA0 = xh + (size_t)(p0 >= 0 ? (p0 >> 1) : 0) * HD + cp * 8;
  const _Float16* gA1 = xh + (size_t)(p1 >= 0 ? (p1 >> 1) : 0) * HD + cp * 8;
  const _Float16* gB0 = wpk + ((size_t)e * NPK + (size_t)ct * 128 + srow) * HD + cp * 8;
  const _Float16* gB1 = gB0 + (size_t)16 * HD;

  auto stage = [&](int sl, int k0) {
    gl_lds16(gA0 + k0, &As[sl][wv * 1024]);
    gl_lds16(gA1 + k0, &As[sl][wv * 1024 + 512]);
    gl_lds16(gB0 + k0, &Bs[sl][wv * 1024]);
    gl_lds16(gB1 + k0, &Bs[sl][wv * 1024 + 512]);
  };

  const f32x4 z4 = {0.f, 0.f, 0.f, 0.f};
  f32x4 acc[4][4];
#pragma unroll
  for (int m = 0; m < 4; ++m)
#pragma unroll
    for (int n = 0; n < 4; ++n) acc[m][n] = z4;

  const int fr = lane & 15, kq = lane >> 4;
  const int wrow = (wv >> 1) * 64, wcol = (wv & 1) * 64;
  int aoff[4], boff[4];
#pragma unroll
  for (int m = 0; m < 4; ++m) {
    int r = wrow + m * 16 + fr;
    aoff[m] = r * 32 + (kq ^ ((r >> 1) & 3)) * 8;
  }
#pragma unroll
  for (int n = 0; n < 4; ++n) {
    int r = wcol + n * 16 + fr;
    boff[n] = r * 32 + (kq ^ ((r >> 1) & 3)) * 8;
  }

  stage(0, 0);
  __syncthreads();

  const int NS = HD / 32;  // 64
  for (int ks = 0; ks < NS; ++ks) {
    const int buf = ks & 1;
    if (ks + 1 < NS) stage(buf ^ 1, (ks + 1) * 32);
    f16x8 fa[4], fb[4];
#pragma unroll
    for (int m = 0; m < 4; ++m) fa[m] = *(const f16x8*)&As[buf][aoff[m]];
#pragma unroll
    for (int n = 0; n < 4; ++n) fb[n] = *(const f16x8*)&Bs[buf][boff[n]];
    __builtin_amdgcn_s_setprio(1);
#pragma unroll
    for (int m = 0; m < 4; ++m)
#pragma unroll
      for (int n = 0; n < 4; ++n)
        acc[m][n] = __builtin_amdgcn_mfma_f32_16x16x32_f16(fa[m], fb[n], acc[m][n], 0, 0, 0);
    __builtin_amdgcn_s_setprio(0);
    __syncthreads();
  }

  // epilogue: packed cols -> h1 = acc[m][n], h2 = acc[m][n+2]
  const int wn = wv & 1;
  const int rbase = wrow + kq * 4;
#pragma unroll
  for (int m = 0; m < 4; ++m) {
#pragma unroll
    for (int n = 0; n < 2; ++n) {
      const int f = ct * 64 + wn * 32 + n * 16 + fr;
#pragma unroll
      for (int j = 0; j < 4; ++j) {
        int rl = rbase + m * 16 + j;
        int pr = row_pair[rl];
        if (pr >= 0) {
          float h1 = acc[m][n][j], h2 = acc[m][n + 2][j];
          float sv = h1 / (1.f + __expf(-h1));
          act[(size_t)pr * FFN + f] = (_Float16)(sv * h2);
        }
      }
    }
  }
}

// ============ Stage B: out += w * (act @ w3h^T). same structure ============
__global__ __launch_bounds__(256, 3) void k_ffn2(const _Float16* __restrict__ act,
                                                 const _Float16* __restrict__ w3h,
                                                 const int* __restrict__ lists,
                                                 const int* __restrict__ cnt,
                                                 const float* __restrict__ tokw,
                                                 float* __restrict__ out) {
  const int bid = blockIdx.x;
  const int xk = bid & 7;
  const int sq = bid >> 3;
  const int rt = sq & 63;
  const int q  = sq >> 6;                       // 0..15
  const int e  = q & 7;
  const int ct = ((xk - e) & 7) + 8 * (q >> 3); // 0..15
  const int count = cnt[e];
  if (rt * 128 >= count) return;
  const int tid = threadIdx.x, lane = tid & 63, wv = tid >> 6;

  __shared__ __align__(16) _Float16 As[2][4096];
  __shared__ __align__(16) _Float16 Bs[2][4096];
  __shared__ int row_pair[128];
  __shared__ float row_w[128];

  if (tid < 128) {
    int rg = rt * 128 + tid;
    int pr = (rg < count) ? lists[e * TT + rg] : -1;
    row_pair[tid] = pr;
    row_w[tid] = (pr >= 0) ? tokw[pr] : 0.f;
  }
  __syncthreads();

  const int lr = lane >> 2;
  const int srow = wv * 32 + lr;
  const int cp = (lane & 3) ^ ((srow >> 1) & 3);
  const int p0 = row_pair[srow], p1 = row_pair[srow + 16];
  const _Float16* gA0 = act + (size_t)(p0 >= 0 ? p0 : 0) * FFN + cp * 8;
  const _Float16* gA1 = act + (size_t)(p1 >= 0 ? p1 : 0) * FFN + cp * 8;
  const _Float16* gB0 = w3h + ((size_t)e * HD + (size_t)ct * 128 + srow) * FFN + cp * 8;
  const _Float16* gB1 = gB0 + (size_t)16 * FFN;

  auto stage = [&](int sl, int k0) {
    gl_lds16(gA0 + k0, &As[sl][wv * 1024]);
    gl_lds16(gA1 + k0, &As[sl][wv * 1024 + 512]);
    gl_lds16(gB0 + k0, &Bs[sl][wv * 1024]);
    gl_lds16(gB1 + k0, &Bs[sl][wv * 1024 + 512]);
  };

  const f32x4 z4 = {0.f, 0.f, 0.f, 0.f};
  f32x4 acc[4][4];
#pragma unroll
  for (int m = 0; m < 4; ++m)
#pragma unroll
    for (int n = 0; n < 4; ++n) acc[m][n] = z4;

  const int fr = lane & 15, kq = lane >> 4;
  const int wrow = (wv >> 1) * 64, wcol = (wv & 1) * 64;
  int aoff[4], boff[4];
#pragma unroll
  for (int m = 0; m < 4; ++m) {
    int r = wrow + m * 16 + fr;
    aoff[m] = r * 32 + (kq ^ ((r >> 1) & 3)) * 8;
  }
#pragma unroll
  for (int n = 0; n < 4; ++n) {
    int r = wcol + n * 16 + fr;
    boff[n] = r * 32 + (kq ^ ((r >> 1) & 3)) * 8;
  }

  stage(0, 0);
  __syncthreads();

  const int NS = FFN / 32;  // 176
  for (int ks = 0; ks < NS; ++ks) {
    const int buf = ks & 1;
    if (ks + 1 < NS) stage(buf ^ 1, (ks + 1) * 32);
    f16x8 fa[4], fb[4];
#pragma unroll
    for (int m = 0; m < 4; ++m) fa[m] = *(const f16x8*)&As[buf][aoff[m]];
#pragma unroll
    for (int n = 0; n < 4; ++n) fb[n] = *(const f16x8*)&Bs[buf][boff[n]];
    __builtin_amdgcn_s_setprio(1);
#pragma unroll
    for (int m = 0; m < 4; ++m)
#pragma unroll
      for (int n = 0; n < 4; ++n)
        acc[m][n] = __builtin_amdgcn_mfma_f32_16x16x32_f16(fa[m], fb[n], acc[m][n], 0, 0, 0);
    __builtin_amdgcn_s_setprio(0);
    __syncthreads();
  }

  const int rbase = wrow + kq * 4;
#pragma unroll
  for (int m = 0; m < 4; ++m) {
#pragma unroll
    for (int n = 0; n < 4; ++n) {
      const int col = ct * 128 + wcol + n * 16 + fr;
#pragma unroll
      for (int j = 0; j < 4; ++j) {
        int rl = rbase + m * 16 + j;
        int pr = row_pair[rl];
        if (pr >= 0) {
          float v = acc[m][n][j] * row_w[rl];
          unsafeAtomicAdd(out + (size_t)(pr >> 1) * HD + col, v);
        }
      }
    }
  }
}

extern "C" void kernel_launch(void* const* d_in, const int* in_sizes, int n_in,
                              void* d_out, int out_size, void* d_ws, size_t ws_size,
                              hipStream_t stream) {
  (void)in_sizes; (void)n_in; (void)out_size; (void)ws_size;
  const float* x    = (const float*)d_in[0];
  const float* wg   = (const float*)d_in[1];
  const float* wge  = (const float*)d_in[2];
  const float* fc11 = (const float*)d_in[3];
  const float* fc12 = (const float*)d_in[4];
  const float* fc2  = (const float*)d_in[5];
  float* out    = (float*)d_out;
  float* logits = out + (size_t)TT * HD;

  char* ws = (char*)d_ws;
  float* wr      = (float*)(ws + OFF_WR);
  int*   cnt     = (int*)(ws + OFF_CNT);
  int*   lists   = (int*)(ws + OFF_LISTS);
  float* tokw    = (float*)(ws + OFF_TOKW);
  _Float16* act  = (_Float16*)(ws + OFF_ACT);
  _Float16* xh   = (_Float16*)(ws + OFF_XH);
  _Float16* wpk  = (_Float16*)(ws + OFF_WPK);
  _Float16* w3h  = (_Float16*)(ws + OFF_W3H);

  hipMemsetAsync(out, 0, (size_t)TT * HD * sizeof(float), stream);
  hipMemsetAsync(cnt, 0, NE * sizeof(int), stream);

  k_prep<<<dim3((HD * NE + 255) / 256), 256, 0, stream>>>(wg, wge, wr);
  k_router<<<dim3(TT), 256, 0, stream>>>(x, wr, logits, tokw, lists, cnt);

  k_cvt<<<dim3(2048), 256, 0, stream>>>(x, xh, (long)TT * HD / 8);
  k_cvtpack<<<dim3(2048), 256, 0, stream>>>(fc11, fc12, wpk);

  k_ffn1<<<dim3(64 * 88 * NE), 256, 0, stream>>>(xh, wpk, lists, cnt, act);

  // w3h reuses the wpk region — stream-ordered after ffn1 finished reading it
  k_cvt<<<dim3(2048), 256, 0, stream>>>(fc2, w3h, (long)NE * HD * FFN / 8);

  k_ffn2<<<dim3(64 * 16 * NE), 256, 0, stream>>>(act, w3h, lists, cnt, tokw, out);
}

// Round 10
// 2193.397 us; speedup vs baseline: 2.2723x; 1.0455x over previous
//
#include <hip/hip_runtime.h>
#include <stdint.h>

#define TT 8192
#define HD 2048
#define FFN 5632
#define NE 8
#define NPK 11264   // packed [w1|w2] rows per expert (2*FFN)

typedef float f32x4 __attribute__((ext_vector_type(4)));
typedef _Float16 f16x8 __attribute__((ext_vector_type(8)));
typedef unsigned int u32;

// workspace layout (bytes)
#define OFF_WR    0ul
#define OFF_CNT   65536ul
#define OFF_LISTS 66048ul
#define OFF_TOKW  328192ul
#define OFF_ACT   1048576ul                    // 16384*5632*2      = 184549376
#define OFF_XH    (OFF_ACT + 184549376ul)      // 8192*2048*2       = 33554432
#define OFF_WPK   (OFF_XH + 33554432ul)        // 8*11264*2048*2    = 369098752
#define OFF_W3H   OFF_WPK                      // fc2h reuses WPK (stream-ordered)

__device__ __forceinline__ void gl_lds16(const void* g, void* s) {
  __builtin_amdgcn_global_load_lds((const __attribute__((address_space(1))) u32*)g,
                                   (__attribute__((address_space(3))) u32*)s, 16, 0, 0);
}

__device__ __forceinline__ f16x8 cvt8(f32x4 a, f32x4 b) {
  f16x8 r;
  r[0] = (_Float16)a[0]; r[1] = (_Float16)a[1]; r[2] = (_Float16)a[2]; r[3] = (_Float16)a[3];
  r[4] = (_Float16)b[0]; r[5] = (_Float16)b[1]; r[6] = (_Float16)b[2]; r[7] = (_Float16)b[3];
  return r;
}

__global__ __launch_bounds__(256) void k_cvt(const float* __restrict__ in,
                                             _Float16* __restrict__ out, long n8) {
  long i = (long)blockIdx.x * 256 + threadIdx.x;
  const long stride = (long)gridDim.x * 256;
  for (; i < n8; i += stride) {
    f32x4 a = ((const f32x4*)in)[i * 2];
    f32x4 b = ((const f32x4*)in)[i * 2 + 1];
    ((f16x8*)out)[i] = cvt8(a, b);
  }
}

// pack [fc1_1 | fc1_2] -> wpk (per 128-row tile: bit6 = wn, bit5 = which matrix, bit4 = n&1)
__global__ __launch_bounds__(256) void k_cvtpack(const float* __restrict__ fc11,
                                                 const float* __restrict__ fc12,
                                                 _Float16* __restrict__ wpk) {
  const long total = (long)NE * NPK * 256;  // 8-elem chunks
  long i8 = (long)blockIdx.x * 256 + threadIdx.x;
  const long stride = (long)gridDim.x * 256;
  for (; i8 < total; i8 += stride) {
    int k8 = (int)(i8 & 255);
    long qe = i8 >> 8;
    int q = (int)(qe % NPK);
    int e = (int)(qe / NPK);
    int c = q & 127;
    int f = (q >> 7) * 64 + ((c >> 6) & 1) * 32 + ((c >> 4) & 1) * 16 + (c & 15);
    const float* src = ((c >> 5) & 1 ? fc12 : fc11) + ((size_t)e * FFN + f) * HD + k8 * 8;
    f32x4 a = *(const f32x4*)src;
    f32x4 b = *(const f32x4*)(src + 4);
    *(f16x8*)(wpk + qe * HD + (size_t)k8 * 8) = cvt8(a, b);
  }
}

__global__ __launch_bounds__(256) void k_prep(const float* __restrict__ wg,
                                              const float* __restrict__ wge,
                                              float* __restrict__ wr) {
  int i = blockIdx.x * 256 + threadIdx.x;
  if (i < HD * NE) wr[i] = 0.5f * (wge[i] + wg[i]);
}

__global__ __launch_bounds__(256) void k_router(const float* __restrict__ x,
                                                const float* __restrict__ wr,
                                                float* __restrict__ logits,
                                                float* __restrict__ tokw,
                                                int* __restrict__ lists,
                                                int* __restrict__ cnt) {
  const int t = blockIdx.x, tid = threadIdx.x;
  const float* xr = x + (size_t)t * HD;
  float acc[NE];
#pragma unroll
  for (int e = 0; e < NE; ++e) acc[e] = 0.f;
  for (int h = tid; h < HD; h += 256) {
    float xv = xr[h];
    const float* w = wr + h * NE;
#pragma unroll
    for (int e = 0; e < NE; ++e) acc[e] = fmaf(xv, w[e], acc[e]);
  }
#pragma unroll
  for (int e = 0; e < NE; ++e)
#pragma unroll
    for (int off = 32; off; off >>= 1)
      acc[e] += __shfl_xor(acc[e], off, 64);
  __shared__ float red[4][NE];
  int wv = tid >> 6;
  if ((tid & 63) == 0)
    for (int e = 0; e < NE; ++e) red[wv][e] = acc[e];
  __syncthreads();
  if (tid == 0) {
    float l[NE];
#pragma unroll
    for (int e = 0; e < NE; ++e) l[e] = red[0][e] + red[1][e] + red[2][e] + red[3][e];
#pragma unroll
    for (int e = 0; e < NE; ++e) logits[(size_t)t * NE + e] = l[e];
    int i0 = 0;
    for (int e = 1; e < NE; ++e) if (l[e] > l[i0]) i0 = e;
    int i1 = -1;
    for (int e = 0; e < NE; ++e) if (e != i0 && (i1 < 0 || l[e] > l[i1])) i1 = e;
    float p1 = __expf(l[i1] - l[i0]);
    float s = 1.f + p1;
    tokw[t * 2]     = 1.f / s;
    tokw[t * 2 + 1] = p1 / s;
    int q0 = atomicAdd(&cnt[i0], 1);
    lists[i0 * TT + q0] = t * 2;
    int q1 = atomicAdd(&cnt[i1], 1);
    lists[i1 * TT + q1] = t * 2 + 1;
  }
}

// ============ Stage A: act = silu(h1)*h2, h = xh @ wpk^T (gathered rows) ============
// 128x128 tile, BK=32, 4 waves 2x2 (wave 64x64). Double-buffer + __syncthreads.
// Grid: XCD-pinned supertiles — per XCD, R=4 rt-blocks (2MB A, L2-pinned) sweep all ct.
__global__ __launch_bounds__(256, 3) void k_ffn1(const _Float16* __restrict__ xh,
                                                 const _Float16* __restrict__ wpk,
                                                 const int* __restrict__ lists,
                                                 const int* __restrict__ cnt,
                                                 _Float16* __restrict__ act) {
  // decode: xk=XCD; slot(0..15) -> (e = slot&7, rh = slot>>3); r = ((xk-e)&7)+8*rh;
  // within slot: ct (0..87) sweeps with rt_in (0..3) innermost; rt = r*4+rt_in.
  const int bid = blockIdx.x;
  const int xk = bid & 7;
  const int sq = bid >> 3;                 // 0..5631
  const int slot = sq / 352;               // 0..15
  const int within = sq - slot * 352;
  const int ct = within >> 2;              // 0..87
  const int rt_in = within & 3;
  const int e = slot & 7;
  const int r = ((xk - e) & 7) + ((slot >> 3) << 3);  // 0..15
  const int rt = r * 4 + rt_in;            // 0..63
  const int count = cnt[e];
  if (rt * 128 >= count) return;
  const int tid = threadIdx.x, lane = tid & 63, wv = tid >> 6;

  __shared__ __align__(16) _Float16 As[2][4096];
  __shared__ __align__(16) _Float16 Bs[2][4096];
  __shared__ int row_pair[128];

  if (tid < 128) {
    int rg = rt * 128 + tid;
    row_pair[tid] = (rg < count) ? lists[e * TT + rg] : -1;
  }
  __syncthreads();

  // staging: wave wv stages rows wv*32..+31 of A and B (2 gl_lds each), XOR chunk perm
  const int lr = lane >> 2;
  const int srow = wv * 32 + lr;
  const int cp = (lane & 3) ^ ((srow >> 1) & 3);
  const int p0 = row_pair[srow], p1 = row_pair[srow + 16];
  const _Float16* gA0 = xh + (size_t)(p0 >= 0 ? (p0 >> 1) : 0) * HD + cp * 8;
  const _Float16* gA1 = xh + (size_t)(p1 >= 0 ? (p1 >> 1) : 0) * HD + cp * 8;
  const _Float16* gB0 = wpk + ((size_t)e * NPK + (size_t)ct * 128 + srow) * HD + cp * 8;
  const _Float16* gB1 = gB0 + (size_t)16 * HD;

  auto stage = [&](int sl, int k0) {
    gl_lds16(gA0 + k0, &As[sl][wv * 1024]);
    gl_lds16(gA1 + k0, &As[sl][wv * 1024 + 512]);
    gl_lds16(gB0 + k0, &Bs[sl][wv * 1024]);
    gl_lds16(gB1 + k0, &Bs[sl][wv * 1024 + 512]);
  };

  const f32x4 z4 = {0.f, 0.f, 0.f, 0.f};
  f32x4 acc[4][4];
#pragma unroll
  for (int m = 0; m < 4; ++m)
#pragma unroll
    for (int n = 0; n < 4; ++n) acc[m][n] = z4;

  const int fr = lane & 15, kq = lane >> 4;
  const int wrow = (wv >> 1) * 64, wcol = (wv & 1) * 64;
  int aoff[4], boff[4];
#pragma unroll
  for (int m = 0; m < 4; ++m) {
    int rr = wrow + m * 16 + fr;
    aoff[m] = rr * 32 + (kq ^ ((rr >> 1) & 3)) * 8;
  }
#pragma unroll
  for (int n = 0; n < 4; ++n) {
    int rr = wcol + n * 16 + fr;
    boff[n] = rr * 32 + (kq ^ ((rr >> 1) & 3)) * 8;
  }

  stage(0, 0);
  __syncthreads();

  const int NS = HD / 32;  // 64
  for (int ks = 0; ks < NS; ++ks) {
    const int buf = ks & 1;
    if (ks + 1 < NS) stage(buf ^ 1, (ks + 1) * 32);
    f16x8 fa[4], fb[4];
#pragma unroll
    for (int m = 0; m < 4; ++m) fa[m] = *(const f16x8*)&As[buf][aoff[m]];
#pragma unroll
    for (int n = 0; n < 4; ++n) fb[n] = *(const f16x8*)&Bs[buf][boff[n]];
    __builtin_amdgcn_s_setprio(1);
#pragma unroll
    for (int m = 0; m < 4; ++m)
#pragma unroll
      for (int n = 0; n < 4; ++n)
        acc[m][n] = __builtin_amdgcn_mfma_f32_16x16x32_f16(fa[m], fb[n], acc[m][n], 0, 0, 0);
    __builtin_amdgcn_s_setprio(0);
    __syncthreads();
  }

  // epilogue: packed cols -> h1 = acc[m][n], h2 = acc[m][n+2]
  const int wn = wv & 1;
  const int rbase = wrow + kq * 4;
#pragma unroll
  for (int m = 0; m < 4; ++m) {
#pragma unroll
    for (int n = 0; n < 2; ++n) {
      const int f = ct * 64 + wn * 32 + n * 16 + fr;
#pragma unroll
      for (int j = 0; j < 4; ++j) {
        int rl = rbase + m * 16 + j;
        int pr = row_pair[rl];
        if (pr >= 0) {
          float h1 = acc[m][n][j], h2 = acc[m][n + 2][j];
          float sv = h1 / (1.f + __expf(-h1));
          act[(size_t)pr * FFN + f] = (_Float16)(sv * h2);
        }
      }
    }
  }
}

// ============ Stage B: out += w * (act @ w3h^T). same inner structure ============
// Grid: per XCD, slot = expert; 2 B-panels (2.8MB, L2-pinned) swept by rt, ct_in innermost.
__global__ __launch_bounds__(256, 3) void k_ffn2(const _Float16* __restrict__ act,
                                                 const _Float16* __restrict__ w3h,
                                                 const int* __restrict__ lists,
                                                 const int* __restrict__ cnt,
                                                 const float* __restrict__ tokw,
                                                 float* __restrict__ out) {
  const int bid = blockIdx.x;
  const int xk = bid & 7;
  const int sq = bid >> 3;                 // 0..1023
  const int e = sq >> 7;                   // 0..7
  const int within = sq & 127;
  const int rt = within >> 1;              // 0..63
  const int ct = (((xk - e) & 7) << 1) + (within & 1);  // 0..15
  const int count = cnt[e];
  if (rt * 128 >= count) return;
  const int tid = threadIdx.x, lane = tid & 63, wv = tid >> 6;

  __shared__ __align__(16) _Float16 As[2][4096];
  __shared__ __align__(16) _Float16 Bs[2][4096];
  __shared__ int row_pair[128];
  __shared__ float row_w[128];

  if (tid < 128) {
    int rg = rt * 128 + tid;
    int pr = (rg < count) ? lists[e * TT + rg] : -1;
    row_pair[tid] = pr;
    row_w[tid] = (pr >= 0) ? tokw[pr] : 0.f;
  }
  __syncthreads();

  const int lr = lane >> 2;
  const int srow = wv * 32 + lr;
  const int cp = (lane & 3) ^ ((srow >> 1) & 3);
  const int p0 = row_pair[srow], p1 = row_pair[srow + 16];
  const _Float16* gA0 = act + (size_t)(p0 >= 0 ? p0 : 0) * FFN + cp * 8;
  const _Float16* gA1 = act + (size_t)(p1 >= 0 ? p1 : 0) * FFN + cp * 8;
  const _Float16* gB0 = w3h + ((size_t)e * HD + (size_t)ct * 128 + srow) * FFN + cp * 8;
  const _Float16* gB1 = gB0 + (size_t)16 * FFN;

  auto stage = [&](int sl, int k0) {
    gl_lds16(gA0 + k0, &As[sl][wv * 1024]);
    gl_lds16(gA1 + k0, &As[sl][wv * 1024 + 512]);
    gl_lds16(gB0 + k0, &Bs[sl][wv * 1024]);
    gl_lds16(gB1 + k0, &Bs[sl][wv * 1024 + 512]);
  };

  const f32x4 z4 = {0.f, 0.f, 0.f, 0.f};
  f32x4 acc[4][4];
#pragma unroll
  for (int m = 0; m < 4; ++m)
#pragma unroll
    for (int n = 0; n < 4; ++n) acc[m][n] = z4;

  const int fr = lane & 15, kq = lane >> 4;
  const int wrow = (wv >> 1) * 64, wcol = (wv & 1) * 64;
  int aoff[4], boff[4];
#pragma unroll
  for (int m = 0; m < 4; ++m) {
    int rr = wrow + m * 16 + fr;
    aoff[m] = rr * 32 + (kq ^ ((rr >> 1) & 3)) * 8;
  }
#pragma unroll
  for (int n = 0; n < 4; ++n) {
    int rr = wcol + n * 16 + fr;
    boff[n] = rr * 32 + (kq ^ ((rr >> 1) & 3)) * 8;
  }

  stage(0, 0);
  __syncthreads();

  const int NS = FFN / 32;  // 176
  for (int ks = 0; ks < NS; ++ks) {
    const int buf = ks & 1;
    if (ks + 1 < NS) stage(buf ^ 1, (ks + 1) * 32);
    f16x8 fa[4], fb[4];
#pragma unroll
    for (int m = 0; m < 4; ++m) fa[m] = *(const f16x8*)&As[buf][aoff[m]];
#pragma unroll
    for (int n = 0; n < 4; ++n) fb[n] = *(const f16x8*)&Bs[buf][boff[n]];
    __builtin_amdgcn_s_setprio(1);
#pragma unroll
    for (int m = 0; m < 4; ++m)
#pragma unroll
      for (int n = 0; n < 4; ++n)
        acc[m][n] = __builtin_amdgcn_mfma_f32_16x16x32_f16(fa[m], fb[n], acc[m][n], 0, 0, 0);
    __builtin_amdgcn_s_setprio(0);
    __syncthreads();
  }

  const int rbase = wrow + kq * 4;
#pragma unroll
  for (int m = 0; m < 4; ++m) {
#pragma unroll
    for (int n = 0; n < 4; ++n) {
      const int col = ct * 128 + wcol + n * 16 + fr;
#pragma unroll
      for (int j = 0; j < 4; ++j) {
        int rl = rbase + m * 16 + j;
        int pr = row_pair[rl];
        if (pr >= 0) {
          float v = acc[m][n][j] * row_w[rl];
          unsafeAtomicAdd(out + (size_t)(pr >> 1) * HD + col, v);
        }
      }
    }
  }
}

extern "C" void kernel_launch(void* const* d_in, const int* in_sizes, int n_in,
                              void* d_out, int out_size, void* d_ws, size_t ws_size,
                              hipStream_t stream) {
  (void)in_sizes; (void)n_in; (void)out_size; (void)ws_size;
  const float* x    = (const float*)d_in[0];
  const float* wg   = (const float*)d_in[1];
  const float* wge  = (const float*)d_in[2];
  const float* fc11 = (const float*)d_in[3];
  const float* fc12 = (const float*)d_in[4];
  const float* fc2  = (const float*)d_in[5];
  float* out    = (float*)d_out;
  float* logits = out + (size_t)TT * HD;

  char* ws = (char*)d_ws;
  float* wr      = (float*)(ws + OFF_WR);
  int*   cnt     = (int*)(ws + OFF_CNT);
  int*   lists   = (int*)(ws + OFF_LISTS);
  float* tokw    = (float*)(ws + OFF_TOKW);
  _Float16* act  = (_Float16*)(ws + OFF_ACT);
  _Float16* xh   = (_Float16*)(ws + OFF_XH);
  _Float16* wpk  = (_Float16*)(ws + OFF_WPK);
  _Float16* w3h  = (_Float16*)(ws + OFF_W3H);

  hipMemsetAsync(out, 0, (size_t)TT * HD * sizeof(float), stream);
  hipMemsetAsync(cnt, 0, NE * sizeof(int), stream);

  k_prep<<<dim3((HD * NE + 255) / 256), 256, 0, stream>>>(wg, wge, wr);
  k_router<<<dim3(TT), 256, 0, stream>>>(x, wr, logits, tokw, lists, cnt);

  k_cvt<<<dim3(2048), 256, 0, stream>>>(x, xh, (long)TT * HD / 8);
  k_cvtpack<<<dim3(2048), 256, 0, stream>>>(fc11, fc12, wpk);

  k_ffn1<<<dim3(64 * 88 * NE), 256, 0, stream>>>(xh, wpk, lists, cnt, act);

  // w3h reuses the wpk region — stream-ordered after ffn1 finished reading it
  k_cvt<<<dim3(2048), 256, 0, stream>>>(fc2, w3h, (long)NE * HD * FFN / 8);

  k_ffn2<<<dim3(64 * 16 * NE), 256, 0, stream>>>(act, w3h, lists, cnt, tokw, out);
}